// Round 3
// baseline (222.930 us; speedup 1.0000x reference)
//
#include <hip/hip_runtime.h>
#include <stdint.h>
#include <stddef.h>

typedef _Float16 f16;
typedef f16 f16x4 __attribute__((ext_vector_type(4)));
typedef f16 f16x8 __attribute__((ext_vector_type(8)));
typedef float f32x4 __attribute__((ext_vector_type(4)));
typedef unsigned long long u64;

#define DEV __device__ __forceinline__

constexpr int Bb = 4, Nn = 8192, Mm = 2048, C1 = 128, C2 = 256;
constexpr int K0 = 384, CO = 256;

// ---------------------------------------------------------------- async 16B global->LDS
DEV void async16(const void* g, void* l) {
  __builtin_amdgcn_global_load_lds((const __attribute__((address_space(1))) void*)g,
                                   (__attribute__((address_space(3))) void*)l, 16, 0, 0);
}

DEV u64 minu64(u64 a, u64 b) { return a < b ? a : b; }
DEV u64 maxu64(u64 a, u64 b) { return a < b ? b : a; }

// ---------------------------------------------------------------- 0) per-batch bitonic sort of known by z
// skey[b][p] = (x, y, z, |k|^2) sorted by z ascending; sidx[b][p] = original index.
__global__ __launch_bounds__(1024) void zsort_kernel(const float* __restrict__ known,
                                                     float4* __restrict__ skey, int* __restrict__ sidx)
{
  __shared__ float zs[2048];
  __shared__ int   is[2048];
  const int t = threadIdx.x, b = blockIdx.x;
  for (int i = t; i < 2048; i += 1024) { zs[i] = known[(b * 2048 + i) * 3 + 2]; is[i] = i; }
  __syncthreads();
  for (int k = 2; k <= 2048; k <<= 1)
    for (int j = k >> 1; j > 0; j >>= 1) {
      int i = ((t & ~(j - 1)) << 1) | (t & (j - 1));
      int p = i | j;
      bool up = ((i & k) == 0);
      float a = zs[i], c = zs[p];
      bool sw = up ? (c < a) : (c > a);
      if (sw) { zs[i] = c; zs[p] = a; int tm = is[i]; is[i] = is[p]; is[p] = tm; }
      __syncthreads();
    }
  for (int i = t; i < 2048; i += 1024) {
    int s = is[i];
    float kx = known[(b * 2048 + s) * 3 + 0];
    float ky = known[(b * 2048 + s) * 3 + 1];
    float kz = zs[i];
    float kk = __fadd_rn(__fadd_rn(__fmul_rn(kx, kx), __fmul_rn(ky, ky)), __fmul_rn(kz, kz));
    skey[b * 2048 + i] = make_float4(kx, ky, kz, kk);
    sidx[b * 2048 + i] = s;
  }
}

// ---------------------------------------------------------------- 1) three_nn: wave-per-query, z-pruned, np-exact
// Per-lane top-3 as u64 key (dd_bits<<32 | m): u64 compare = exact (d, idx) lexicographic order.
// dd computed in np association order -> identical bits to the full scan; pruning only skips
// candidates whose 1-D z-gap^2 already exceeds a conservative upper bound on the final d3.
__global__ __launch_bounds__(256) void knn_wave(
    const float* __restrict__ unknown, const float4* __restrict__ skey, const int* __restrict__ sidx,
    int* __restrict__ oidx, float* __restrict__ ow)
{
  const int t = threadIdx.x, l = t & 63;
  const int qg = blockIdx.x * 4 + (t >> 6);
  const int b = qg >> 13, n = qg & 8191;
  const float4* sk = skey + b * 2048;
  const int*    si = sidx + b * 2048;
  const float*  up = unknown + (size_t)(b * Nn + n) * 3;
  float ux = up[0], uy = up[1], uz = up[2];
  float uu = __fadd_rn(__fadd_rn(__fmul_rn(ux, ux), __fmul_rn(uy, uy)), __fmul_rn(uz, uz));

  // coarse position of uz in the sorted z array (64 samples, stride 32)
  float zp = ((const float*)sk)[l * 128 + 2];
  int P = __popcll(__ballot(zp <= uz)) * 32;
  int ci0 = min(max(P - 32, 0), 2047) >> 6;

  u64 k1 = ~0ull, k2 = ~0ull, k3 = ~0ull;

  auto proc = [&](int c) -> float2 {
    float4 f = sk[c * 64 + l];
    int mi = si[c * 64 + l];
    float dot = __fadd_rn(__fadd_rn(__fmul_rn(ux, f.x), __fmul_rn(uy, f.y)), __fmul_rn(uz, f.z));
    float dd  = __fadd_rn(__fsub_rn(uu, __fadd_rn(dot, dot)), f.w); // (uu - 2*dot) + kk, np order
    dd = fmaxf(dd, 0.0f);                                            // keep sign bit clear for u64 order
    u64 key = ((u64)__float_as_uint(dd) << 32) | (unsigned)mi;
    bool c1 = key < k1, c2 = key < k2, c3 = key < k3;
    k3 = c3 ? (c2 ? k2 : key) : k3;
    k2 = c2 ? (c1 ? k1 : key) : k2;
    k1 = c1 ? key : k1;
    return make_float2(__shfl(f.z, 0), __shfl(f.z, 63)); // (z_first, z_last) of chunk
  };

  proc(ci0);
  int cl = ci0 - 1, cr = ci0 + 1;
  bool openL = (cl >= 0), openR = (cr <= 31);
  while (openL || openR) {
    // conservative wave-wide bound: min over lanes of local d3 (NaN while <3 seen -> no close)
    float d3w = __uint_as_float((unsigned)(k3 >> 32));
#pragma unroll
    for (int msk = 1; msk < 64; msk <<= 1) d3w = fminf(d3w, __shfl_xor(d3w, msk));
    float bnd = d3w * 1.0001f + 1e-6f;
    if (openR) {
      float2 e = proc(cr);
      float g = __fsub_rn(e.y, uz);
      if (g > 0.0f && __fmul_rn(g, g) > bnd) openR = false;
      if (++cr > 31) openR = false;
    }
    if (openL) {
      float2 e = proc(cl);
      float g = __fsub_rn(uz, e.x);
      if (g > 0.0f && __fmul_rn(g, g) > bnd) openL = false;
      if (--cl < 0) openL = false;
    }
  }

  // butterfly merge of per-lane sorted triples (u64 lexicographic, exact tie-break)
#pragma unroll
  for (int msk = 1; msk < 64; msk <<= 1) {
    u64 b1 = __shfl_xor(k1, msk), b2 = __shfl_xor(k2, msk), b3 = __shfl_xor(k3, msk);
    u64 r1 = minu64(k1, b1);
    u64 r2 = minu64(maxu64(k1, b1), minu64(k2, b2));
    u64 r3 = minu64(minu64(maxu64(k2, b1), maxu64(k1, b2)), minu64(k3, b3));
    k1 = r1; k2 = r2; k3 = r3;
  }

  if (l == 0) {
    float d1 = __uint_as_float((unsigned)(k1 >> 32));
    float d2 = __uint_as_float((unsigned)(k2 >> 32));
    float d3 = __uint_as_float((unsigned)(k3 >> 32));
    float t1 = sqrtf(d1), t2 = sqrtf(d2), t3 = sqrtf(d3);
    float r1 = 1.f / (t1 + 1e-8f), r2 = 1.f / (t2 + 1e-8f), r3 = 1.f / (t3 + 1e-8f);
    float rs = __fadd_rn(__fadd_rn(r1, r2), r3);
    int base = (b * Nn + n) * 3;
    oidx[base + 0] = (int)(unsigned)k1;
    oidx[base + 1] = (int)(unsigned)k2;
    oidx[base + 2] = (int)(unsigned)k3;
    ow[base + 0] = r1 / rs; ow[base + 1] = r2 / rs; ow[base + 2] = r3 / rs;
  }
}

// ---------------------------------------------------------------- 2) known_feats (B,C2,M) f32 -> kfT (B,M,C2) f16
__global__ __launch_bounds__(256) void kft_kernel(const float* __restrict__ kf, f16* __restrict__ kfT)
{
  __shared__ f16 tile[64][72];
  const int t = threadIdx.x;
  const int m0 = blockIdx.x * 64, c0 = blockIdx.y * 64, b = blockIdx.z;
  const int lm = t & 63, row = t >> 6;
#pragma unroll
  for (int j = 0; j < 16; ++j) {
    int c = row + j * 4;
    tile[lm][c] = (f16)kf[(size_t)(b * C2 + c0 + c) * Mm + m0 + lm];
  }
  __syncthreads();
#pragma unroll
  for (int j = 0; j < 16; ++j) {
    int m = row + j * 4;
    kfT[(size_t)(b * Mm + m0 + m) * C2 + c0 + lm] = tile[m][lm];
  }
}

// ---------------------------------------------------------------- 3) weight fp32->fp16
__global__ void wcvt_kernel(const float* __restrict__ W0, const float* __restrict__ W1,
                            f16* __restrict__ Wh0, f16* __restrict__ Wh1)
{
  int i = blockIdx.x * 256 + threadIdx.x;
  if (i < CO * K0) Wh0[i] = (f16)W0[i];
  if (i < CO * CO) Wh1[i] = (f16)W1[i];
}

// ---------------------------------------------------------------- 4) three_interpolate -> x0[b][n][0..255] (f16, K-fast)
__global__ __launch_bounds__(256) void interp_kernel(
    const f16* __restrict__ kfT, const int* __restrict__ idx, const float* __restrict__ wts,
    f16* __restrict__ x0)
{
  const int t = threadIdx.x;
  const int wv = t >> 6, l = t & 63;
  const int b = blockIdx.y;
  const int n0 = blockIdx.x * 64;
  for (int it = 0; it < 16; ++it) {
    int q = n0 + it * 4 + wv;                 // wave-uniform -> scalar idx/weight loads
    int base = (b * Nn + q) * 3;
    int i0 = idx[base + 0], i1 = idx[base + 1], i2 = idx[base + 2];
    float w0 = wts[base + 0], w1 = wts[base + 1], w2 = wts[base + 2];
    const f16x4* r0 = (const f16x4*)(kfT + (size_t)(b * Mm + i0) * C2);
    const f16x4* r1 = (const f16x4*)(kfT + (size_t)(b * Mm + i1) * C2);
    const f16x4* r2 = (const f16x4*)(kfT + (size_t)(b * Mm + i2) * C2);
    f16x4 a0 = r0[l], a1 = r1[l], a2 = r2[l];
    f16x4 o;
#pragma unroll
    for (int j = 0; j < 4; ++j) {
      float v = w0 * (float)a0[j] + w1 * (float)a1[j] + w2 * (float)a2[j];
      o[j] = (f16)v;
    }
    *(f16x4*)(x0 + (size_t)(b * Nn + q) * K0 + l * 4) = o;
  }
}

// ---------------------------------------------------------------- 5) unknow_feats (B,C1,N) f32 -> x0[b][n][256..383] f16
__global__ __launch_bounds__(256) void uft_kernel(const float* __restrict__ uf, f16* __restrict__ x0)
{
  __shared__ f16 tile[64][136];
  const int t = threadIdx.x;
  const int b = blockIdx.y;
  const int n0 = blockIdx.x * 64;
  const int ln = t & 63, cr = t >> 6;
#pragma unroll
  for (int j = 0; j < 32; ++j) {
    int c = j * 4 + cr;
    tile[ln][c] = (f16)uf[(size_t)(b * C1 + c) * Nn + n0 + ln];
  }
  __syncthreads();
  const int ch = t & 15, rr = t >> 4;
#pragma unroll
  for (int j = 0; j < 4; ++j) {
    int n = j * 16 + rr;
    f16x8 v = *(const f16x8*)&tile[n][ch * 8];
    *(f16x8*)(x0 + (size_t)(b * Nn + n0 + n) * K0 + C2 + ch * 8) = v;
  }
}

// ---------------------------------------------------------------- 6) fp16 MFMA GEMM + BN + ReLU
// C[m][n] = sum_k A[m][k]*X[b][n][k]; 128x128 tile, BK=64, 2x2 waves, 16x16x32 MFMA.
// LDS: row-major [row][8 octets of 16B], stored octet p = o ^ (row&7) so linear async16
// staging coexists with fully conflict-free ds_read_b128 fragment reads.
// 1D grid with XCD pairing: the 2 m-tiles sharing a B-tile are 8 dispatch-IDs apart.
template<int KD, bool TRANS>
__global__ __launch_bounds__(256) void gemm_kernel(
    const f16* __restrict__ A, const f16* __restrict__ X,
    const float* __restrict__ bias, const float* __restrict__ gam,
    const float* __restrict__ bet, const float* __restrict__ rmean,
    const float* __restrict__ rvar,
    f16* __restrict__ outT,     // TRANS:  (B,N,256) f16 (layer-0 -> layer-1 input)
    float* __restrict__ outF)   // !TRANS: (B,256,N) f32 (final output)
{
  constexpr int STAGE = 32768;                       // A 16KB + B 16KB
  constexpr int TB = TRANS ? (128 * 136 * 2) : STAGE;
  constexpr int BNOFF = (TB > STAGE ? TB : STAGE);
  __shared__ __align__(16) char lds[BNOFF + 1024];

  const int t = threadIdx.x;
  const int w = t >> 6, l = t & 63;
  const int gid = blockIdx.x;
  const int nl = gid & 7, mtile = (gid >> 3) & 1, nh = (gid >> 4) & 7, b = gid >> 7;
  const int n0 = (nh * 8 + nl) * 128;
  const int m0 = mtile * 128;

  float* bnS = (float*)(lds + BNOFF);
  float* bnH = bnS + 128;
  if (t < 128) {
    int c = m0 + t;
    float sc = gam[c] / sqrtf(rvar[c] + 1e-5f);
    bnS[t] = sc;
    bnH[t] = (bias[c] - rmean[c]) * sc + bet[c];
  }

  // staging: slot s = i*256 + t, row r = s>>3, LDS octet p = s&7 holds global octet o = p ^ (r&7)
  const f16* gA[4]; const f16* gB[4];
#pragma unroll
  for (int i = 0; i < 4; ++i) {
    int s = i * 256 + t;
    int r = s >> 3, o = (s & 7) ^ (r & 7);
    gA[i] = A + (size_t)(m0 + r) * KD + o * 8;
    gB[i] = X + (size_t)(b * Nn + n0 + r) * KD + o * 8;
  }

  const int lm = l & 15, qq = l >> 4;
  int offA[4], offB[4];
#pragma unroll
  for (int i = 0; i < 4; ++i) {
    int m = (w >> 1) * 64 + i * 16 + lm;
    offA[i] = m * 128 + (qq ^ (m & 7)) * 16;
    int nn2 = (w & 1) * 64 + i * 16 + lm;
    offB[i] = 16384 + nn2 * 128 + (qq ^ (nn2 & 7)) * 16;
  }

  f32x4 acc[4][4] = {};
  for (int k0 = 0; k0 < KD; k0 += 64) {
    __syncthreads();                         // LDS free to overwrite
#pragma unroll
    for (int i = 0; i < 4; ++i) {
      async16(gA[i], lds + (i * 256 + w * 64) * 16);
      async16(gB[i], lds + 16384 + (i * 256 + w * 64) * 16);
    }
    __syncthreads();                         // vmcnt(0) drained by compiler before barrier
#pragma unroll
    for (int i = 0; i < 4; ++i) { gA[i] += 64; gB[i] += 64; }
#pragma unroll
    for (int h = 0; h < 2; ++h) {            // two K=32 halves per stage (octets qq / qq+4)
      f16x8 af[4], bf[4];
#pragma unroll
      for (int i = 0; i < 4; ++i) {
        af[i] = *(const f16x8*)(lds + (offA[i] ^ (h << 6)));
        bf[i] = *(const f16x8*)(lds + (offB[i] ^ (h << 6)));
      }
#pragma unroll
      for (int i = 0; i < 4; ++i)
#pragma unroll
        for (int j = 0; j < 4; ++j)
          acc[i][j] = __builtin_amdgcn_mfma_f32_16x16x32_f16(af[i], bf[j], acc[i][j], 0, 0, 0);
    }
  }

  const int wm = (w >> 1) * 64, wn = (w & 1) * 64;
  if constexpr (TRANS) {
    __syncthreads();                         // all frag reads done before LDS reuse
    f16* T = (f16*)lds;                      // [128 n][136 m-pitch]
#pragma unroll
    for (int i = 0; i < 4; ++i) {
      int mb = wm + i * 16 + qq * 4;
      float s0v = bnS[mb + 0], s1v = bnS[mb + 1], s2v = bnS[mb + 2], s3v = bnS[mb + 3];
      float h0v = bnH[mb + 0], h1v = bnH[mb + 1], h2v = bnH[mb + 2], h3v = bnH[mb + 3];
#pragma unroll
      for (int j = 0; j < 4; ++j) {
        int nn2 = wn + j * 16 + lm;
        f16x4 v;
        v[0] = (f16)fmaxf(fmaf(acc[i][j][0], s0v, h0v), 0.f);
        v[1] = (f16)fmaxf(fmaf(acc[i][j][1], s1v, h1v), 0.f);
        v[2] = (f16)fmaxf(fmaf(acc[i][j][2], s2v, h2v), 0.f);
        v[3] = (f16)fmaxf(fmaf(acc[i][j][3], s3v, h3v), 0.f);
        *(f16x4*)&T[nn2 * 136 + mb] = v;
      }
    }
    __syncthreads();
    const int ch = t & 15, rr = t >> 4;
#pragma unroll
    for (int j = 0; j < 8; ++j) {
      int nn2 = j * 16 + rr;
      f16x8 v = *(const f16x8*)&T[nn2 * 136 + ch * 8];
      *(f16x8*)(outT + (size_t)(b * Nn + n0 + nn2) * CO + m0 + ch * 8) = v;
    }
  } else {
#pragma unroll
    for (int i = 0; i < 4; ++i) {
#pragma unroll
      for (int r = 0; r < 4; ++r) {
        int ml = wm + i * 16 + qq * 4 + r;
        float sc = bnS[ml], sh = bnH[ml];
#pragma unroll
        for (int j = 0; j < 4; ++j) {
          int nn2 = wn + j * 16 + lm;
          float y = fmaxf(fmaf(acc[i][j][r], sc, sh), 0.f);
          outF[(size_t)(b * CO + m0 + ml) * Nn + n0 + nn2] = y;
        }
      }
    }
  }
}

// ---------------------------------------------------------------- launch
extern "C" void kernel_launch(void* const* d_in, const int* in_sizes, int n_in,
                              void* d_out, int out_size, void* d_ws, size_t ws_size,
                              hipStream_t stream)
{
  const float* unknown = (const float*)d_in[0];
  const float* known   = (const float*)d_in[1];
  const float* uf      = (const float*)d_in[2];
  const float* kf      = (const float*)d_in[3];
  const float* W0  = (const float*)d_in[4];
  const float* b0  = (const float*)d_in[5];
  const float* g0  = (const float*)d_in[6];
  const float* be0 = (const float*)d_in[7];
  const float* rm0 = (const float*)d_in[8];
  const float* rv0 = (const float*)d_in[9];
  const float* W1  = (const float*)d_in[10];
  const float* b1  = (const float*)d_in[11];
  const float* g1  = (const float*)d_in[12];
  const float* be1 = (const float*)d_in[13];
  const float* rm1 = (const float*)d_in[14];
  const float* rv1 = (const float*)d_in[15];

  char* ws = (char*)d_ws;
  // ws layout (bytes): idx/wts persist; skey/sidx live inside the kfT region
  // (consumed by knn_wave BEFORE kft_kernel overwrites it — stream-ordered).
  int*    idx   = (int*)   (ws + 0);          // B*N*3 i32   = 384 KB
  float*  wts   = (float*) (ws + 393216);     // B*N*3 f32   = 384 KB
  f16*    kfT   = (f16*)   (ws + 786432);     // B*M*C2 f16  = 4 MB
  float4* skey  = (float4*)(ws + 786432);     // B*2048*16 B = 128 KB (aliases kfT, freed before kft)
  int*    sidx  = (int*)   (ws + 917504);     // B*2048*4 B  = 32 KB
  f16*    Wh0   = (f16*)   (ws + 4980736);    // 256*384 f16
  f16*    Wh1   = (f16*)   (ws + 5177344);    // 256*256 f16
  f16*    x0    = (f16*)   (ws + 5308416);    // B*N*384 f16 = 25.2 MB
  f16*    x1    = (f16*)   (ws + 30474240);   // B*N*256 f16 = 16.8 MB
  float*  out   = (float*)d_out;              // (B,256,N) f32

  zsort_kernel <<<dim3(Bb), 1024, 0, stream>>>(known, skey, sidx);
  knn_wave     <<<dim3(Bb * Nn / 4), 256, 0, stream>>>(unknown, skey, sidx, idx, wts);
  kft_kernel   <<<dim3(Mm / 64, C2 / 64, Bb), 256, 0, stream>>>(kf, kfT);
  wcvt_kernel  <<<dim3((CO * K0 + 255) / 256), 256, 0, stream>>>(W0, W1, Wh0, Wh1);
  interp_kernel<<<dim3(Nn / 64, Bb), 256, 0, stream>>>(kfT, idx, wts, x0);
  uft_kernel   <<<dim3(Nn / 64, Bb), 256, 0, stream>>>(uf, x0);
  gemm_kernel<K0, true> <<<dim3(512), 256, 0, stream>>>(Wh0, x0, b0, g0, be0, rm0, rv0, x1, nullptr);
  gemm_kernel<CO, false><<<dim3(512), 256, 0, stream>>>(Wh1, x1, b1, g1, be1, rm1, rv1, nullptr, out);
}

// Round 4
// 173.721 us; speedup vs baseline: 1.2833x; 1.2833x over previous
//
#include <hip/hip_runtime.h>
#include <stdint.h>
#include <stddef.h>

typedef _Float16 f16;
typedef f16 f16x4 __attribute__((ext_vector_type(4)));
typedef f16 f16x8 __attribute__((ext_vector_type(8)));
typedef float f32x4 __attribute__((ext_vector_type(4)));

#define DEV __device__ __forceinline__

constexpr int Bb = 4, Nn = 8192, Mm = 2048, C1 = 128, C2 = 256;
constexpr int K0 = 384, CO = 256;

// ---------------------------------------------------------------- 1) three_nn (np-mimic fp32) — R2 version (proven 46.5us)
__global__ __launch_bounds__(256) void knn_kernel(
    const float* __restrict__ unknown, const float* __restrict__ known,
    int* __restrict__ oidx, float* __restrict__ ow)
{
  __shared__ float4 kpts[Mm];        // x,y,z,|k|^2  (32 KB)
  const int t  = threadIdx.x;
  const int bx = blockIdx.x;
  const int b  = bx >> 9;            // N/16 = 512 blocks per batch
  const int n0 = (bx & 511) * 16;

#pragma unroll
  for (int j = 0; j < 8; ++j) {
    int m = t + j * 256;
    float kx = known[(b * Mm + m) * 3 + 0];
    float ky = known[(b * Mm + m) * 3 + 1];
    float kz = known[(b * Mm + m) * 3 + 2];
    float kk = __fadd_rn(__fadd_rn(__fmul_rn(kx, kx), __fmul_rn(ky, ky)), __fmul_rn(kz, kz));
    kpts[m] = make_float4(kx, ky, kz, kk);
  }
  const int s = t & 15;              // slice: m = it*16 + s
  const int q = n0 + (t >> 4);
  float ux = unknown[(b * Nn + q) * 3 + 0];
  float uy = unknown[(b * Nn + q) * 3 + 1];
  float uz = unknown[(b * Nn + q) * 3 + 2];
  float uu = __fadd_rn(__fadd_rn(__fmul_rn(ux, ux), __fmul_rn(uy, uy)), __fmul_rn(uz, uz));
  __syncthreads();

  float d1 = 1e30f, d2 = 1e30f, d3 = 1e30f;
  int   i1 = 0, i2 = 0, i3 = 0;
#pragma unroll 4
  for (int it = 0; it < Mm / 16; ++it) {
    int m = it * 16 + s;
    float4 kp = kpts[m];
    float dot = __fadd_rn(__fadd_rn(__fmul_rn(ux, kp.x), __fmul_rn(uy, kp.y)), __fmul_rn(uz, kp.z));
    float dd  = __fadd_rn(__fsub_rn(uu, __fadd_rn(dot, dot)), kp.w); // (uu - 2*dot) + kk
    bool c1 = dd < d1, c2 = dd < d2, c3 = dd < d3;
    i3 = c3 ? (c2 ? i2 : m) : i3;
    i2 = c2 ? (c1 ? i1 : m) : i2;
    i1 = c1 ? m : i1;
    d3 = __builtin_amdgcn_fmed3f(dd, d2, d3);
    d2 = __builtin_amdgcn_fmed3f(dd, d1, d2);
    d1 = fminf(dd, d1);
  }

#pragma unroll
  for (int mask = 1; mask <= 8; mask <<= 1) {
    float e1 = __shfl_xor(d1, mask), e2 = __shfl_xor(d2, mask), e3 = __shfl_xor(d3, mask);
    int   j1 = __shfl_xor(i1, mask), j2 = __shfl_xor(i2, mask), j3 = __shfl_xor(i3, mask);
#pragma unroll
    for (int u = 0; u < 3; ++u) {
      float e = u == 0 ? e1 : (u == 1 ? e2 : e3);
      int   j = u == 0 ? j1 : (u == 1 ? j2 : j3);
      bool c3 = (e < d3) || (e == d3 && j < i3);
      bool c2 = (e < d2) || (e == d2 && j < i2);
      bool c1 = (e < d1) || (e == d1 && j < i1);
      d3 = c3 ? (c2 ? d2 : e) : d3;  i3 = c3 ? (c2 ? i2 : j) : i3;
      d2 = c2 ? (c1 ? d1 : e) : d2;  i2 = c2 ? (c1 ? i1 : j) : i2;
      d1 = c1 ? e : d1;              i1 = c1 ? j : i1;
    }
  }

  if (s == 0) {
    float t1 = sqrtf(fmaxf(d1, 0.f)), t2 = sqrtf(fmaxf(d2, 0.f)), t3 = sqrtf(fmaxf(d3, 0.f));
    float r1 = 1.f / (t1 + 1e-8f), r2 = 1.f / (t2 + 1e-8f), r3 = 1.f / (t3 + 1e-8f);
    float rs = __fadd_rn(__fadd_rn(r1, r2), r3);
    int base = (b * Nn + q) * 3;
    oidx[base + 0] = i1; oidx[base + 1] = i2; oidx[base + 2] = i3;
    ow[base + 0] = r1 / rs; ow[base + 1] = r2 / rs; ow[base + 2] = r3 / rs;
  }
}

// ---------------------------------------------------------------- 2) known_feats (B,C2,M) f32 -> kfT (B,M,C2) f16
__global__ __launch_bounds__(256) void kft_kernel(const float* __restrict__ kf, f16* __restrict__ kfT)
{
  __shared__ f16 tile[64][72];
  const int t = threadIdx.x;
  const int m0 = blockIdx.x * 64, c0 = blockIdx.y * 64, b = blockIdx.z;
  const int lm = t & 63, row = t >> 6;
#pragma unroll
  for (int j = 0; j < 16; ++j) {
    int c = row + j * 4;
    tile[lm][c] = (f16)kf[(size_t)(b * C2 + c0 + c) * Mm + m0 + lm];
  }
  __syncthreads();
#pragma unroll
  for (int j = 0; j < 16; ++j) {
    int m = row + j * 4;
    kfT[(size_t)(b * Mm + m0 + m) * C2 + c0 + lm] = tile[m][lm];
  }
}

// ---------------------------------------------------------------- 3) weight fp32->fp16
__global__ void wcvt_kernel(const float* __restrict__ W0, const float* __restrict__ W1,
                            f16* __restrict__ Wh0, f16* __restrict__ Wh1)
{
  int i = blockIdx.x * 256 + threadIdx.x;
  if (i < CO * K0) Wh0[i] = (f16)W0[i];
  if (i < CO * CO) Wh1[i] = (f16)W1[i];
}

// ---------------------------------------------------------------- 4) fused interp + concat + MLP0 + MLP1
// 256 blocks x 512 threads (1 block/CU). Per block: 128 queries, all 256 out-channels.
// LDS: B0 [128 n][48 k-octets, oct^=(n&7)] = 96KB at 0; B1 [128 n][32 co-octets] = 64KB at 0 (reuse);
//      bn tables at 98304..102400. A-operands read straight from global (L2-resident) -> no
//      barriers inside either K-loop.
__global__ __launch_bounds__(512) void mlp_fused(
    const f16* __restrict__ Wh0, const f16* __restrict__ Wh1,
    const f16* __restrict__ kfT, const float* __restrict__ uf,
    const int* __restrict__ idx, const float* __restrict__ wts,
    const float* __restrict__ bs0, const float* __restrict__ g0,
    const float* __restrict__ be0, const float* __restrict__ rm0, const float* __restrict__ rv0,
    const float* __restrict__ bs1, const float* __restrict__ g1,
    const float* __restrict__ be1, const float* __restrict__ rm1, const float* __restrict__ rv1,
    float* __restrict__ out)
{
  __shared__ __align__(16) char lds[102400];
  const int t = threadIdx.x;
  const int w = t >> 6, l = t & 63, lm = l & 15, qq = l >> 4;
  const int gid = blockIdx.x;
  const int b = gid >> 6, n0 = (gid & 63) * 128;

  float* bn0S = (float*)(lds + 98304);
  float* bn0H = (float*)(lds + 99328);
  float* bn1S = (float*)(lds + 100352);
  float* bn1H = (float*)(lds + 101376);
  if (t < 256) {
    float sc = g0[t] / sqrtf(rv0[t] + 1e-5f);
    bn0S[t] = sc; bn0H[t] = (bs0[t] - rm0[t]) * sc + be0[t];
  } else {
    int c = t - 256;
    float sc = g1[c] / sqrtf(rv1[c] + 1e-5f);
    bn1S[c] = sc; bn1H[c] = (bs1[c] - rm1[c]) * sc + be1[c];
  }

  // ---- stage B0, interp part (k = 0..255): thread = (n = t>>2, kg = t&3 -> 64 k each)
  {
    const int n = t >> 2, kg = t & 3;
    const int base = (b * Nn + n0 + n) * 3;
    int i0 = idx[base], i1 = idx[base + 1], i2 = idx[base + 2];
    float w0 = wts[base], w1 = wts[base + 1], w2 = wts[base + 2];
    f16 w0h = (f16)w0, w1h = (f16)w1, w2h = (f16)w2;
    f16x8 w0v = {w0h, w0h, w0h, w0h, w0h, w0h, w0h, w0h};
    f16x8 w1v = {w1h, w1h, w1h, w1h, w1h, w1h, w1h, w1h};
    f16x8 w2v = {w2h, w2h, w2h, w2h, w2h, w2h, w2h, w2h};
    const f16x8* r0 = (const f16x8*)(kfT + (size_t)(b * Mm + i0) * C2 + kg * 64);
    const f16x8* r1 = (const f16x8*)(kfT + (size_t)(b * Mm + i1) * C2 + kg * 64);
    const f16x8* r2 = (const f16x8*)(kfT + (size_t)(b * Mm + i2) * C2 + kg * 64);
#pragma unroll
    for (int j = 0; j < 8; ++j) {
      f16x8 o = r0[j] * w0v + r1[j] * w1v + r2[j] * w2v;
      int oct = kg * 8 + j;
      *(f16x8*)(lds + n * 768 + ((oct ^ (n & 7)) * 16)) = o;
    }
  }
  // ---- stage B0, unknow_feats part (k = 256..383): thread = (n = t&127, cb = (t>>7)*32)
  {
    const int n = t & 127, cb = (t >> 7) * 32;
    const float* src = uf + (size_t)(b * C1 + cb) * Nn + n0 + n;
#pragma unroll
    for (int jj = 0; jj < 4; ++jj) {
      f16x8 v;
#pragma unroll
      for (int e = 0; e < 8; ++e) v[e] = (f16)src[(size_t)(jj * 8 + e) * Nn];
      int oct = 32 + (cb >> 3) + jj;
      *(f16x8*)(lds + n * 768 + ((oct ^ (n & 7)) * 16)) = v;
    }
  }
  __syncthreads();

  const int wm = (w >> 1) * 64, wn = (w & 1) * 64;
  f32x4 acc[4][4] = {};

  // ---- layer 0: K=384, 12 k32-steps, no barriers (A from global, B0 static in LDS)
  for (int ks = 0; ks < 12; ++ks) {
    const int kb = ks * 4;
    f16x8 af[4], bf[4];
#pragma unroll
    for (int i = 0; i < 4; ++i)
      af[i] = *(const f16x8*)(Wh0 + (size_t)(wm + i * 16 + lm) * K0 + (kb + qq) * 8);
#pragma unroll
    for (int j = 0; j < 4; ++j) {
      int n = wn + j * 16 + lm;
      bf[j] = *(const f16x8*)(lds + n * 768 + (((kb + qq) ^ (n & 7)) * 16));
    }
#pragma unroll
    for (int i = 0; i < 4; ++i)
#pragma unroll
      for (int j = 0; j < 4; ++j)
        acc[i][j] = __builtin_amdgcn_mfma_f32_16x16x32_f16(af[i], bf[j], acc[i][j], 0, 0, 0);
  }
  __syncthreads();                       // all B0 reads done before overwrite

  // ---- layer-0 epilogue: BN+ReLU -> f16 into B1 [128 n][32 co-octets, oct^=(n&7)]
#pragma unroll
  for (int i = 0; i < 4; ++i) {
    const int mq = wm + i * 16 + qq * 4;
    f32x4 s4 = *(const f32x4*)&bn0S[mq];
    f32x4 h4 = *(const f32x4*)&bn0H[mq];
#pragma unroll
    for (int j = 0; j < 4; ++j) {
      int n = wn + j * 16 + lm;
      f16x4 v;
#pragma unroll
      for (int r = 0; r < 4; ++r) v[r] = (f16)fmaxf(fmaf(acc[i][j][r], s4[r], h4[r]), 0.f);
      *(f16x4*)(lds + n * 512 + (((mq >> 3) ^ (n & 7)) * 16) + (mq & 7) * 2) = v;
    }
  }
  __syncthreads();

  // ---- layer 1: K=256, 8 k32-steps, no barriers
#pragma unroll
  for (int i = 0; i < 4; ++i)
#pragma unroll
    for (int j = 0; j < 4; ++j) acc[i][j] = f32x4{0.f, 0.f, 0.f, 0.f};
  for (int ks = 0; ks < 8; ++ks) {
    const int kb = ks * 4;
    f16x8 af[4], bf[4];
#pragma unroll
    for (int i = 0; i < 4; ++i)
      af[i] = *(const f16x8*)(Wh1 + (size_t)(wm + i * 16 + lm) * CO + (kb + qq) * 8);
#pragma unroll
    for (int j = 0; j < 4; ++j) {
      int n = wn + j * 16 + lm;
      bf[j] = *(const f16x8*)(lds + n * 512 + (((kb + qq) ^ (n & 7)) * 16));
    }
#pragma unroll
    for (int i = 0; i < 4; ++i)
#pragma unroll
      for (int j = 0; j < 4; ++j)
        acc[i][j] = __builtin_amdgcn_mfma_f32_16x16x32_f16(af[i], bf[j], acc[i][j], 0, 0, 0);
  }

  // ---- layer-1 epilogue: BN+ReLU -> f32 out (B,256,N)
#pragma unroll
  for (int i = 0; i < 4; ++i) {
    const int mq = wm + i * 16 + qq * 4;
    f32x4 s4 = *(const f32x4*)&bn1S[mq];
    f32x4 h4 = *(const f32x4*)&bn1H[mq];
#pragma unroll
    for (int r = 0; r < 4; ++r) {
      const int m = mq + r;
#pragma unroll
      for (int j = 0; j < 4; ++j) {
        int n = wn + j * 16 + lm;
        out[(size_t)(b * CO + m) * Nn + n0 + n] = fmaxf(fmaf(acc[i][j][r], s4[r], h4[r]), 0.f);
      }
    }
  }
}

// ---------------------------------------------------------------- launch
extern "C" void kernel_launch(void* const* d_in, const int* in_sizes, int n_in,
                              void* d_out, int out_size, void* d_ws, size_t ws_size,
                              hipStream_t stream)
{
  const float* unknown = (const float*)d_in[0];
  const float* known   = (const float*)d_in[1];
  const float* uf      = (const float*)d_in[2];
  const float* kf      = (const float*)d_in[3];
  const float* W0  = (const float*)d_in[4];
  const float* b0  = (const float*)d_in[5];
  const float* g0  = (const float*)d_in[6];
  const float* be0 = (const float*)d_in[7];
  const float* rm0 = (const float*)d_in[8];
  const float* rv0 = (const float*)d_in[9];
  const float* W1  = (const float*)d_in[10];
  const float* b1  = (const float*)d_in[11];
  const float* g1  = (const float*)d_in[12];
  const float* be1 = (const float*)d_in[13];
  const float* rm1 = (const float*)d_in[14];
  const float* rv1 = (const float*)d_in[15];

  char* ws = (char*)d_ws;
  int*   idx = (int*)  (ws + 0);          // B*N*3 i32   = 384 KB
  float* wts = (float*)(ws + 393216);     // B*N*3 f32   = 384 KB
  f16*   kfT = (f16*)  (ws + 786432);     // B*M*C2 f16  = 4 MB
  f16*   Wh0 = (f16*)  (ws + 4980736);    // 256*384 f16
  f16*   Wh1 = (f16*)  (ws + 5177344);    // 256*256 f16
  float* out = (float*)d_out;             // (B,256,N) f32

  knn_kernel <<<dim3(Bb * (Nn / 16)), 256, 0, stream>>>(unknown, known, idx, wts);
  kft_kernel <<<dim3(Mm / 64, C2 / 64, Bb), 256, 0, stream>>>(kf, kfT);
  wcvt_kernel<<<dim3((CO * K0 + 255) / 256), 256, 0, stream>>>(W0, W1, Wh0, Wh1);
  mlp_fused  <<<dim3(Bb * (Nn / 128)), 512, 0, stream>>>(
      Wh0, Wh1, kfT, uf, idx, wts,
      b0, g0, be0, rm0, rv0, b1, g1, be1, rm1, rv1, out);
}

// Round 5
// 171.744 us; speedup vs baseline: 1.2980x; 1.0115x over previous
//
#include <hip/hip_runtime.h>
#include <stdint.h>
#include <stddef.h>

typedef _Float16 f16;
typedef f16 f16x4 __attribute__((ext_vector_type(4)));
typedef f16 f16x8 __attribute__((ext_vector_type(8)));
typedef float f32x4 __attribute__((ext_vector_type(4)));

#define DEV __device__ __forceinline__

constexpr int Bb = 4, Nn = 8192, Mm = 2048, C1 = 128, C2 = 256;
constexpr int K0 = 384, CO = 256;

// ---------------------------------------------------------------- 1) three_nn (np-mimic fp32) — proven 43us, unchanged
__global__ __launch_bounds__(256) void knn_kernel(
    const float* __restrict__ unknown, const float* __restrict__ known,
    int* __restrict__ oidx, float* __restrict__ ow)
{
  __shared__ float4 kpts[Mm];        // x,y,z,|k|^2  (32 KB)
  const int t  = threadIdx.x;
  const int bx = blockIdx.x;
  const int b  = bx >> 9;            // N/16 = 512 blocks per batch
  const int n0 = (bx & 511) * 16;

#pragma unroll
  for (int j = 0; j < 8; ++j) {
    int m = t + j * 256;
    float kx = known[(b * Mm + m) * 3 + 0];
    float ky = known[(b * Mm + m) * 3 + 1];
    float kz = known[(b * Mm + m) * 3 + 2];
    float kk = __fadd_rn(__fadd_rn(__fmul_rn(kx, kx), __fmul_rn(ky, ky)), __fmul_rn(kz, kz));
    kpts[m] = make_float4(kx, ky, kz, kk);
  }
  const int s = t & 15;              // slice: m = it*16 + s
  const int q = n0 + (t >> 4);
  float ux = unknown[(b * Nn + q) * 3 + 0];
  float uy = unknown[(b * Nn + q) * 3 + 1];
  float uz = unknown[(b * Nn + q) * 3 + 2];
  float uu = __fadd_rn(__fadd_rn(__fmul_rn(ux, ux), __fmul_rn(uy, uy)), __fmul_rn(uz, uz));
  __syncthreads();

  float d1 = 1e30f, d2 = 1e30f, d3 = 1e30f;
  int   i1 = 0, i2 = 0, i3 = 0;
#pragma unroll 4
  for (int it = 0; it < Mm / 16; ++it) {
    int m = it * 16 + s;
    float4 kp = kpts[m];
    float dot = __fadd_rn(__fadd_rn(__fmul_rn(ux, kp.x), __fmul_rn(uy, kp.y)), __fmul_rn(uz, kp.z));
    float dd  = __fadd_rn(__fsub_rn(uu, __fadd_rn(dot, dot)), kp.w); // (uu - 2*dot) + kk
    bool c1 = dd < d1, c2 = dd < d2, c3 = dd < d3;
    i3 = c3 ? (c2 ? i2 : m) : i3;
    i2 = c2 ? (c1 ? i1 : m) : i2;
    i1 = c1 ? m : i1;
    d3 = __builtin_amdgcn_fmed3f(dd, d2, d3);
    d2 = __builtin_amdgcn_fmed3f(dd, d1, d2);
    d1 = fminf(dd, d1);
  }

#pragma unroll
  for (int mask = 1; mask <= 8; mask <<= 1) {
    float e1 = __shfl_xor(d1, mask), e2 = __shfl_xor(d2, mask), e3 = __shfl_xor(d3, mask);
    int   j1 = __shfl_xor(i1, mask), j2 = __shfl_xor(i2, mask), j3 = __shfl_xor(i3, mask);
#pragma unroll
    for (int u = 0; u < 3; ++u) {
      float e = u == 0 ? e1 : (u == 1 ? e2 : e3);
      int   j = u == 0 ? j1 : (u == 1 ? j2 : j3);
      bool c3 = (e < d3) || (e == d3 && j < i3);
      bool c2 = (e < d2) || (e == d2 && j < i2);
      bool c1 = (e < d1) || (e == d1 && j < i1);
      d3 = c3 ? (c2 ? d2 : e) : d3;  i3 = c3 ? (c2 ? i2 : j) : i3;
      d2 = c2 ? (c1 ? d1 : e) : d2;  i2 = c2 ? (c1 ? i1 : j) : i2;
      d1 = c1 ? e : d1;              i1 = c1 ? j : i1;
    }
  }

  if (s == 0) {
    float t1 = sqrtf(fmaxf(d1, 0.f)), t2 = sqrtf(fmaxf(d2, 0.f)), t3 = sqrtf(fmaxf(d3, 0.f));
    float r1 = 1.f / (t1 + 1e-8f), r2 = 1.f / (t2 + 1e-8f), r3 = 1.f / (t3 + 1e-8f);
    float rs = __fadd_rn(__fadd_rn(r1, r2), r3);
    int base = (b * Nn + q) * 3;
    oidx[base + 0] = i1; oidx[base + 1] = i2; oidx[base + 2] = i3;
    ow[base + 0] = r1 / rs; ow[base + 1] = r2 / rs; ow[base + 2] = r3 / rs;
  }
}

// ---------------------------------------------------------------- 2) known_feats (B,C2,M) f32 -> kfT (B,M,C2) f16
__global__ __launch_bounds__(256) void kft_kernel(const float* __restrict__ kf, f16* __restrict__ kfT)
{
  __shared__ f16 tile[64][72];
  const int t = threadIdx.x;
  const int m0 = blockIdx.x * 64, c0 = blockIdx.y * 64, b = blockIdx.z;
  const int lm = t & 63, row = t >> 6;
#pragma unroll
  for (int j = 0; j < 16; ++j) {
    int c = row + j * 4;
    tile[lm][c] = (f16)kf[(size_t)(b * C2 + c0 + c) * Mm + m0 + lm];
  }
  __syncthreads();
#pragma unroll
  for (int j = 0; j < 16; ++j) {
    int m = row + j * 4;
    kfT[(size_t)(b * Mm + m0 + m) * C2 + c0 + lm] = tile[m][lm];
  }
}

// ---------------------------------------------------------------- 3) weights f32 -> f16 in MFMA A-fragment order
// Af[((ks*16 + mg)*64 + lane)*8 + e] = W[m = mg*16 + (lane&15)][k = ks*32 + (lane>>4)*8 + e]
// -> the GEMM's af load is one fully-coalesced 1KB global_load_dwordx4 per wave.
__global__ void wrep_kernel(const float* __restrict__ W0, const float* __restrict__ W1,
                            f16* __restrict__ Af0, f16* __restrict__ Af1)
{
  int id = blockIdx.x * 256 + threadIdx.x;
  if (id < CO * K0) {
    int e = id & 7, lane = (id >> 3) & 63, mg = (id >> 9) & 15, ks = id >> 13;
    int m = mg * 16 + (lane & 15), k = ks * 32 + (lane >> 4) * 8 + e;
    Af0[id] = (f16)W0[m * K0 + k];
  }
  if (id < CO * CO) {
    int e = id & 7, lane = (id >> 3) & 63, mg = (id >> 9) & 15, ks = id >> 13;
    int m = mg * 16 + (lane & 15), k = ks * 32 + (lane >> 4) * 8 + e;
    Af1[id] = (f16)W1[m * CO + k];
  }
}

// ---------------------------------------------------------------- 4) fused interp + concat + MLP0 + MLP1
// 512 blocks x 256 threads (2 blocks/CU, 8 waves/CU). Per block: 64 queries, all 256 out-ch.
// LDS: B0 [64 n][48 k-octets, oct^=(n&7)] = 48KB at 0; B1 [64 n][32 co-octets] = 32KB (overlay);
// bn tables at 49152. A-fragments stream coalesced from pre-swizzled Af0/Af1 (L2-resident),
// prefetched one k-step ahead; K-loops have zero barriers.
__global__ __launch_bounds__(256) void mlp_fused(
    const f16* __restrict__ Af0, const f16* __restrict__ Af1,
    const f16* __restrict__ kfT, const float* __restrict__ uf,
    const int* __restrict__ idx, const float* __restrict__ wts,
    const float* __restrict__ bs0, const float* __restrict__ g0,
    const float* __restrict__ be0, const float* __restrict__ rm0, const float* __restrict__ rv0,
    const float* __restrict__ bs1, const float* __restrict__ g1,
    const float* __restrict__ be1, const float* __restrict__ rm1, const float* __restrict__ rv1,
    float* __restrict__ out)
{
  __shared__ __align__(16) char lds[53248];
  const int t = threadIdx.x;
  const int w = t >> 6, l = t & 63, lm = l & 15, qq = l >> 4;
  const int gid = blockIdx.x;
  const int b = gid >> 7, n0 = (gid & 127) * 64;

  float* bn0S = (float*)(lds + 49152);
  float* bn0H = (float*)(lds + 50176);
  float* bn1S = (float*)(lds + 51200);
  float* bn1H = (float*)(lds + 52224);
  {
    float sc0 = g0[t] / sqrtf(rv0[t] + 1e-5f);
    bn0S[t] = sc0; bn0H[t] = (bs0[t] - rm0[t]) * sc0 + be0[t];
    float sc1 = g1[t] / sqrtf(rv1[t] + 1e-5f);
    bn1S[t] = sc1; bn1H[t] = (bs1[t] - rm1[t]) * sc1 + be1[t];
  }

  // ---- stage B0, interp part (k = 0..255): thread = (n = t>>2, kg = t&3 -> 64 k each)
  {
    const int n = t >> 2, kg = t & 3;
    const int base = (b * Nn + n0 + n) * 3;
    int i0 = idx[base], i1 = idx[base + 1], i2 = idx[base + 2];
    float w0 = wts[base], w1 = wts[base + 1], w2 = wts[base + 2];
    f16 w0h = (f16)w0, w1h = (f16)w1, w2h = (f16)w2;
    f16x8 w0v = {w0h, w0h, w0h, w0h, w0h, w0h, w0h, w0h};
    f16x8 w1v = {w1h, w1h, w1h, w1h, w1h, w1h, w1h, w1h};
    f16x8 w2v = {w2h, w2h, w2h, w2h, w2h, w2h, w2h, w2h};
    const f16x8* r0 = (const f16x8*)(kfT + (size_t)(b * Mm + i0) * C2 + kg * 64);
    const f16x8* r1 = (const f16x8*)(kfT + (size_t)(b * Mm + i1) * C2 + kg * 64);
    const f16x8* r2 = (const f16x8*)(kfT + (size_t)(b * Mm + i2) * C2 + kg * 64);
#pragma unroll
    for (int j = 0; j < 8; ++j) {
      f16x8 o = r0[j] * w0v + r1[j] * w1v + r2[j] * w2v;
      int oct = kg * 8 + j;
      *(f16x8*)(lds + n * 768 + ((oct ^ (n & 7)) * 16)) = o;
    }
  }
  // ---- stage B0, unknow_feats part (k = 256..383): thread = (n = t&63, cb = (t>>6)*32)
  {
    const int n = t & 63, cb = (t >> 6) * 32;
    const float* src = uf + (size_t)(b * C1 + cb) * Nn + n0 + n;
#pragma unroll
    for (int jj = 0; jj < 4; ++jj) {
      f16x8 v;
#pragma unroll
      for (int e = 0; e < 8; ++e) v[e] = (f16)src[(size_t)(jj * 8 + e) * Nn];
      int oct = 32 + (cb >> 3) + jj;
      *(f16x8*)(lds + n * 768 + ((oct ^ (n & 7)) * 16)) = v;
    }
  }
  __syncthreads();

  f32x4 acc[4][4] = {};

  // ---- layer 0: K=384, 12 k32-steps, zero barriers, af prefetched 1 step ahead
  {
    f16x8 af[4];
#pragma unroll
    for (int i = 0; i < 4; ++i)
      af[i] = *(const f16x8*)(Af0 + ((size_t)(0 * 16 + w * 4 + i) * 64 + l) * 8);
    for (int ks = 0; ks < 12; ++ks) {
      f16x8 afn[4];
      if (ks < 11) {
#pragma unroll
        for (int i = 0; i < 4; ++i)
          afn[i] = *(const f16x8*)(Af0 + ((size_t)((ks + 1) * 16 + w * 4 + i) * 64 + l) * 8);
      }
      f16x8 bf[4];
#pragma unroll
      for (int j = 0; j < 4; ++j) {
        int n = j * 16 + lm;
        bf[j] = *(const f16x8*)(lds + n * 768 + (((ks * 4 + qq) ^ (n & 7)) * 16));
      }
#pragma unroll
      for (int i = 0; i < 4; ++i)
#pragma unroll
        for (int j = 0; j < 4; ++j)
          acc[i][j] = __builtin_amdgcn_mfma_f32_16x16x32_f16(af[i], bf[j], acc[i][j], 0, 0, 0);
#pragma unroll
      for (int i = 0; i < 4; ++i) af[i] = afn[i];
    }
  }
  __syncthreads();                       // all B0 reads done before overwrite

  // ---- layer-0 epilogue: BN+ReLU -> f16 into B1 [64 n][32 co-octets, oct^=(n&7)]
#pragma unroll
  for (int i = 0; i < 4; ++i) {
    const int mq = w * 64 + i * 16 + qq * 4;
    f32x4 s4 = *(const f32x4*)&bn0S[mq];
    f32x4 h4 = *(const f32x4*)&bn0H[mq];
#pragma unroll
    for (int j = 0; j < 4; ++j) {
      int n = j * 16 + lm;
      f16x4 v;
#pragma unroll
      for (int r = 0; r < 4; ++r) v[r] = (f16)fmaxf(fmaf(acc[i][j][r], s4[r], h4[r]), 0.f);
      *(f16x4*)(lds + n * 512 + (((mq >> 3) ^ (n & 7)) * 16) + (mq & 7) * 2) = v;
    }
  }
  __syncthreads();

  // ---- layer 1: K=256, 8 k32-steps, zero barriers, prefetched
#pragma unroll
  for (int i = 0; i < 4; ++i)
#pragma unroll
    for (int j = 0; j < 4; ++j) acc[i][j] = f32x4{0.f, 0.f, 0.f, 0.f};
  {
    f16x8 af[4];
#pragma unroll
    for (int i = 0; i < 4; ++i)
      af[i] = *(const f16x8*)(Af1 + ((size_t)(0 * 16 + w * 4 + i) * 64 + l) * 8);
    for (int ks = 0; ks < 8; ++ks) {
      f16x8 afn[4];
      if (ks < 7) {
#pragma unroll
        for (int i = 0; i < 4; ++i)
          afn[i] = *(const f16x8*)(Af1 + ((size_t)((ks + 1) * 16 + w * 4 + i) * 64 + l) * 8);
      }
      f16x8 bf[4];
#pragma unroll
      for (int j = 0; j < 4; ++j) {
        int n = j * 16 + lm;
        bf[j] = *(const f16x8*)(lds + n * 512 + (((ks * 4 + qq) ^ (n & 7)) * 16));
      }
#pragma unroll
      for (int i = 0; i < 4; ++i)
#pragma unroll
        for (int j = 0; j < 4; ++j)
          acc[i][j] = __builtin_amdgcn_mfma_f32_16x16x32_f16(af[i], bf[j], acc[i][j], 0, 0, 0);
#pragma unroll
      for (int i = 0; i < 4; ++i) af[i] = afn[i];
    }
  }

  // ---- layer-1 epilogue: BN+ReLU -> f32 out (B,256,N)
#pragma unroll
  for (int i = 0; i < 4; ++i) {
    const int mq = w * 64 + i * 16 + qq * 4;
    f32x4 s4 = *(const f32x4*)&bn1S[mq];
    f32x4 h4 = *(const f32x4*)&bn1H[mq];
#pragma unroll
    for (int r = 0; r < 4; ++r) {
      const int m = mq + r;
#pragma unroll
      for (int j = 0; j < 4; ++j) {
        int n = j * 16 + lm;
        out[(size_t)(b * CO + m) * Nn + n0 + n] = fmaxf(fmaf(acc[i][j][r], s4[r], h4[r]), 0.f);
      }
    }
  }
}

// ---------------------------------------------------------------- launch
extern "C" void kernel_launch(void* const* d_in, const int* in_sizes, int n_in,
                              void* d_out, int out_size, void* d_ws, size_t ws_size,
                              hipStream_t stream)
{
  const float* unknown = (const float*)d_in[0];
  const float* known   = (const float*)d_in[1];
  const float* uf      = (const float*)d_in[2];
  const float* kf      = (const float*)d_in[3];
  const float* W0  = (const float*)d_in[4];
  const float* b0  = (const float*)d_in[5];
  const float* g0  = (const float*)d_in[6];
  const float* be0 = (const float*)d_in[7];
  const float* rm0 = (const float*)d_in[8];
  const float* rv0 = (const float*)d_in[9];
  const float* W1  = (const float*)d_in[10];
  const float* b1  = (const float*)d_in[11];
  const float* g1  = (const float*)d_in[12];
  const float* be1 = (const float*)d_in[13];
  const float* rm1 = (const float*)d_in[14];
  const float* rv1 = (const float*)d_in[15];

  char* ws = (char*)d_ws;
  int*   idx = (int*)  (ws + 0);          // B*N*3 i32   = 384 KB
  float* wts = (float*)(ws + 393216);     // B*N*3 f32   = 384 KB
  f16*   kfT = (f16*)  (ws + 786432);     // B*M*C2 f16  = 4 MB
  f16*   Af0 = (f16*)  (ws + 4980736);    // 256*384 f16 (fragment-order)
  f16*   Af1 = (f16*)  (ws + 5177344);    // 256*256 f16 (fragment-order)
  float* out = (float*)d_out;             // (B,256,N) f32

  knn_kernel <<<dim3(Bb * (Nn / 16)), 256, 0, stream>>>(unknown, known, idx, wts);
  kft_kernel <<<dim3(Mm / 64, C2 / 64, Bb), 256, 0, stream>>>(kf, kfT);
  wrep_kernel<<<dim3((CO * K0 + 255) / 256), 256, 0, stream>>>(W0, W1, Af0, Af1);
  mlp_fused  <<<dim3(Bb * (Nn / 64)), 256, 0, stream>>>(
      Af0, Af1, kfT, uf, idx, wts,
      b0, g0, be0, rm0, rv0, b1, g1, be1, rm1, rv1, out);
}